// Round 10
// baseline (8581.039 us; speedup 1.0000x reference)
//
#include <hip/hip_runtime.h>
#include <math.h>

#define Bn 64
#define Sn 512
#define Dn 256
#define Hn 512
#define On 128

using short8 = __attribute__((ext_vector_type(8))) short;
using f32x4  = __attribute__((ext_vector_type(4))) float;
typedef unsigned long long u64;

union U8 { unsigned u[4]; short8 s; };

__device__ __forceinline__ ushort f2bf(float f) {
    unsigned u = __float_as_uint(f);
    u = u + 0x7FFFu + ((u >> 16) & 1u);   // round-to-nearest-even
    return (ushort)(u >> 16);
}
__device__ __forceinline__ float bf2f(ushort b) {
    return __uint_as_float(((unsigned)b) << 16);
}
// split 8 consecutive fp32 into hi/lo bf16 fragments
__device__ __forceinline__ void split8(const float* __restrict__ p, short8& hi, short8& lo) {
    #pragma unroll
    for (int j = 0; j < 8; ++j) {
        float w = p[j];
        ushort h = f2bf(w);
        hi[j] = (short)h;
        lo[j] = (short)f2bf(w - bf2f(h));
    }
}
// opaque register pin
__device__ __forceinline__ void pin8(short8& v) { asm volatile("" : "+v"(v)); }

// ---- LLC-coherent access via relaxed agent atomics (proven R6-R9) ----
__device__ __forceinline__ void lda8(const unsigned* p, unsigned* w) {
    const u64* q = (const u64*)p;
    #pragma unroll
    for (int j = 0; j < 4; ++j) {
        u64 v = __hip_atomic_load(q + j, __ATOMIC_RELAXED, __HIP_MEMORY_SCOPE_AGENT);
        w[2*j]   = (unsigned)v;
        w[2*j+1] = (unsigned)(v >> 32);
    }
}
__device__ __forceinline__ void unpack8(const unsigned* w, short8& hi8, short8& lo8) {
    U8 a, b;
    #pragma unroll
    for (int j = 0; j < 4; ++j) {
        a.u[j] = (w[2*j] & 0xffffu) | (w[2*j+1] << 16);
        b.u[j] = (w[2*j] >> 16)     | (w[2*j+1] & 0xffff0000u);
    }
    hi8 = a.s; lo8 = b.s;
}
__device__ __forceinline__ void sta32(unsigned* p, unsigned v) {
    __hip_atomic_store(p, v, __ATOMIC_RELAXED, __HIP_MEMORY_SCOPE_AGENT);
}

// ---- epoch-tagged data: poll 8 consecutive {word, tag} u64s until all tags == tag ----
__device__ __forceinline__ void poll8(const u64* q, unsigned tag, unsigned* w) {
    u64 v[8];
    for (;;) {
        #pragma unroll
        for (int j = 0; j < 8; ++j)
            v[j] = __hip_atomic_load(q + j, __ATOMIC_RELAXED, __HIP_MEMORY_SCOPE_AGENT);
        bool ok = true;
        #pragma unroll
        for (int j = 0; j < 8; ++j) ok &= ((unsigned)(v[j] >> 32) == tag);
        if (ok) break;
        __builtin_amdgcn_s_sleep(1);
    }
    #pragma unroll
    for (int j = 0; j < 8; ++j) w[j] = (unsigned)v[j];
}
__device__ __forceinline__ void st_tag(u64* p, unsigned word, unsigned tag) {
    __hip_atomic_store(p, (u64)word | ((u64)tag << 32), __ATOMIC_RELAXED, __HIP_MEMORY_SCOPE_AGENT);
}

// one-time phase-gate flags
__device__ __forceinline__ void poll_ge(const unsigned* p, unsigned epoch) {
    while (__hip_atomic_load(p, __ATOMIC_RELAXED, __HIP_MEMORY_SCOPE_AGENT) < epoch)
        __builtin_amdgcn_s_sleep(1);
}

__device__ __forceinline__ f32x4 mfma_bf16(short8 a, short8 b, f32x4 c) {
    return __builtin_amdgcn_mfma_f32_16x16x32_bf16(a, b, c, 0, 0, 0);
}

__global__ __launch_bounds__(256, 1) void bilstm_persistent(
    const float* __restrict__ x,
    const float* __restrict__ wih0f, const float* __restrict__ whh0f,
    const float* __restrict__ bih0f, const float* __restrict__ bhh0f,
    const float* __restrict__ wih0b, const float* __restrict__ whh0b,
    const float* __restrict__ bih0b, const float* __restrict__ bhh0b,
    const float* __restrict__ wih1f, const float* __restrict__ whh1f,
    const float* __restrict__ bih1f, const float* __restrict__ bhh1f,
    const float* __restrict__ wih1b, const float* __restrict__ whh1b,
    const float* __restrict__ bih1b, const float* __restrict__ bhh1b,
    const float* __restrict__ fcw,  const float* __restrict__ fcb,
    unsigned* flags,     // [0..256) P1 done, [512..768) P3 done (one-time gates)
    u64* h0_tg,          // [2 parity][2 dir][B][H] {word, tag}
    u64* h1_tg,          // [2 parity][B][H] {word, tag}
    unsigned* h1b_pk,    // [B][H] packed u32
    unsigned* out0_pk,   // [B][S][2H] packed u32
    float* out)
{
    const int bid = blockIdx.x;
    const int tid = threadIdx.x;
    const int l  = tid & 63;    // lane
    const int w  = tid >> 6;    // wave 0..3 (K-split)
    const int lc = l & 15;      // col lane (gate col) / A-row lane (batch)
    const int ks = l >> 4;      // k-segment 0..3 within a 32-k block

    __shared__ float P[4 * 4 * 16 * 20];   // 20KB partials
    __shared__ short8 wl[6144];            // 96KB per-lane weight-lo closet
    __shared__ float hstage[2][Hn];        // 4KB FC staging

    //==================== PHASE 1: layer 0, both dirs, 512 steps ====================
    {
        const int dir = bid >> 7;
        const int hs  = (bid >> 2) & 31;   // 16 hidden units
        const int bt  = bid & 3;           // 16 batches
        unsigned* g1slot = &flags[(dir * 4 + bt) * 32 + hs];
        const float* wih = dir ? wih0b : wih0f;
        const float* whh = dir ? whh0b : whh0f;
        const float* bih = dir ? bih0b : bih0f;
        const float* bhh = dir ? bhh0b : bhh0f;

        // stage weights ONCE: hi -> pinned VGPR, lo -> per-lane LDS
        short8 wh_hi[4][4];
        #pragma unroll
        for (int i = 0; i < 4; ++i) {
            const int k0 = (w * 4 + i) * 32 + ks * 8;
            #pragma unroll
            for (int nt = 0; nt < 4; ++nt) {
                const int r = nt * 512 + hs * 16 + lc;
                short8 hi, lo;
                split8(&whh[(size_t)r * 512 + k0], hi, lo);
                wh_hi[i][nt] = hi;
                wl[(w * 16 + i * 4 + nt) * 64 + l] = lo;
            }
        }
        short8 wx_hi[2][4];
        #pragma unroll
        for (int i = 0; i < 2; ++i) {
            const int k0 = (w * 2 + i) * 32 + ks * 8;
            #pragma unroll
            for (int nt = 0; nt < 4; ++nt) {
                const int r = nt * 512 + hs * 16 + lc;
                short8 hi, lo;
                split8(&wih[(size_t)r * 256 + k0], hi, lo);
                wx_hi[i][nt] = hi;
                wl[4096 + (w * 8 + i * 4 + nt) * 64 + l] = lo;
            }
        }
        #pragma unroll
        for (int i = 0; i < 4; ++i)
            #pragma unroll
            for (int nt = 0; nt < 4; ++nt) pin8(wh_hi[i][nt]);
        #pragma unroll
        for (int i = 0; i < 2; ++i)
            #pragma unroll
            for (int nt = 0; nt < 4; ++nt) pin8(wx_hi[i][nt]);
        const short8* whlo = &wl[(w * 16) * 64 + l];
        const short8* wxlo = &wl[4096 + (w * 8) * 64 + l];

        const int cb = bt * 16 + (tid >> 4);
        const int ch = hs * 16 + (tid & 15);
        float bias_r[4];
        #pragma unroll
        for (int gt = 0; gt < 4; ++gt)
            bias_r[gt] = bih[gt * 512 + ch] + bhh[gt * 512 + ch];
        float c_reg = 0.f;
        const int bA = bt * 16 + lc;

        // xg for step 0
        f32x4 xg0 = {0.f,0.f,0.f,0.f}, xg1 = xg0, xg2 = xg0, xg3 = xg0;
        {
            const int tt = dir ? (Sn - 1) : 0;
            #pragma unroll
            for (int i = 0; i < 2; ++i) {
                const int k0 = (w * 2 + i) * 32 + ks * 8;
                short8 xh, xl;
                split8(&x[((size_t)bA * Sn + tt) * Dn + k0], xh, xl);
                xg0 = mfma_bf16(xh, wx_hi[i][0], xg0); xg0 = mfma_bf16(xl, wx_hi[i][0], xg0); xg0 = mfma_bf16(xh, wxlo[(i*4+0)*64], xg0);
                xg1 = mfma_bf16(xh, wx_hi[i][1], xg1); xg1 = mfma_bf16(xl, wx_hi[i][1], xg1); xg1 = mfma_bf16(xh, wxlo[(i*4+1)*64], xg1);
                xg2 = mfma_bf16(xh, wx_hi[i][2], xg2); xg2 = mfma_bf16(xl, wx_hi[i][2], xg2); xg2 = mfma_bf16(xh, wxlo[(i*4+2)*64], xg2);
                xg3 = mfma_bf16(xh, wx_hi[i][3], xg3); xg3 = mfma_bf16(xl, wx_hi[i][3], xg3); xg3 = mfma_bf16(xh, wxlo[(i*4+3)*64], xg3);
            }
        }

        for (int s = 0; s < Sn; ++s) {
            const int p = s & 1;
            const int t = dir ? (Sn - 1 - s) : s;

            // critical: poll tagged h directly (data IS the flag)
            unsigned hw[4][8];
            #pragma unroll
            for (int i = 0; i < 4; ++i)
                poll8(&h0_tg[(((size_t)p * 2 + dir) * Bn + bA) * Hn + (w * 4 + i) * 32 + ks * 8],
                      (unsigned)s, hw[i]);

            f32x4 acc0 = xg0, acc1 = xg1, acc2 = xg2, acc3 = xg3;
            #pragma unroll
            for (int i = 0; i < 4; ++i) {
                short8 ah, al;
                unpack8(hw[i], ah, al);
                acc0 = mfma_bf16(ah, wh_hi[i][0], acc0); acc0 = mfma_bf16(al, wh_hi[i][0], acc0); acc0 = mfma_bf16(ah, whlo[(i*4+0)*64], acc0);
                acc1 = mfma_bf16(ah, wh_hi[i][1], acc1); acc1 = mfma_bf16(al, wh_hi[i][1], acc1); acc1 = mfma_bf16(ah, whlo[(i*4+1)*64], acc1);
                acc2 = mfma_bf16(ah, wh_hi[i][2], acc2); acc2 = mfma_bf16(al, wh_hi[i][2], acc2); acc2 = mfma_bf16(ah, whlo[(i*4+2)*64], acc2);
                acc3 = mfma_bf16(ah, wh_hi[i][3], acc3); acc3 = mfma_bf16(al, wh_hi[i][3], acc3); acc3 = mfma_bf16(ah, whlo[(i*4+3)*64], acc3);
            }
            *(f32x4*)&P[((w * 4 + 0) * 16 + lc) * 20 + ks * 4] = acc0;
            *(f32x4*)&P[((w * 4 + 1) * 16 + lc) * 20 + ks * 4] = acc1;
            *(f32x4*)&P[((w * 4 + 2) * 16 + lc) * 20 + ks * 4] = acc2;
            *(f32x4*)&P[((w * 4 + 3) * 16 + lc) * 20 + ks * 4] = acc3;
            __syncthreads();

            unsigned word;
            {
                float g4[4];
                #pragma unroll
                for (int gt = 0; gt < 4; ++gt) {
                    float sum = bias_r[gt];
                    #pragma unroll
                    for (int ww = 0; ww < 4; ++ww)
                        sum += P[((ww * 4 + gt) * 16 + (tid & 15)) * 20 + (tid >> 4)];
                    g4[gt] = sum;
                }
                const float ig = 1.f / (1.f + expf(-g4[0]));
                const float fg = 1.f / (1.f + expf(-g4[1]));
                const float gg = tanhf(g4[2]);
                const float og = 1.f / (1.f + expf(-g4[3]));
                c_reg = fg * c_reg + ig * gg;
                const float h = og * tanhf(c_reg);
                const ushort hhv = f2bf(h);
                const ushort hlv = f2bf(h - bf2f(hhv));
                word = (unsigned)hhv | ((unsigned)hlv << 16);
                // CRITICAL store first: tagged h, single 8B atomic
                st_tag(&h0_tg[(((size_t)((s + 1) & 1) * 2 + dir) * Bn + cb) * Hn + ch],
                       word, (unsigned)(s + 1));
            }
            if (s == Sn - 1)
                sta32(&out0_pk[((size_t)cb * Sn + t) * 1024 + dir * 512 + ch], word);

            __syncthreads();   // protects P; also drains stores before the gate flag
            if (s == Sn - 1 && tid == 0)
                __hip_atomic_store(g1slot, (unsigned)Sn, __ATOMIC_RELAXED, __HIP_MEMORY_SCOPE_AGENT);

            // hoisted off critical path: out0 store + next step's x-projection
            if (s < Sn - 1) {
                sta32(&out0_pk[((size_t)cb * Sn + t) * 1024 + dir * 512 + ch], word);
                const int tt = dir ? (Sn - 2 - s) : (s + 1);
                xg0 = {0.f,0.f,0.f,0.f}; xg1 = xg0; xg2 = xg0; xg3 = xg0;
                #pragma unroll
                for (int i = 0; i < 2; ++i) {
                    const int k0 = (w * 2 + i) * 32 + ks * 8;
                    short8 xh, xl;
                    split8(&x[((size_t)bA * Sn + tt) * Dn + k0], xh, xl);
                    xg0 = mfma_bf16(xh, wx_hi[i][0], xg0); xg0 = mfma_bf16(xl, wx_hi[i][0], xg0); xg0 = mfma_bf16(xh, wxlo[(i*4+0)*64], xg0);
                    xg1 = mfma_bf16(xh, wx_hi[i][1], xg1); xg1 = mfma_bf16(xl, wx_hi[i][1], xg1); xg1 = mfma_bf16(xh, wxlo[(i*4+1)*64], xg1);
                    xg2 = mfma_bf16(xh, wx_hi[i][2], xg2); xg2 = mfma_bf16(xl, wx_hi[i][2], xg2); xg2 = mfma_bf16(xh, wxlo[(i*4+2)*64], xg2);
                    xg3 = mfma_bf16(xh, wx_hi[i][3], xg3); xg3 = mfma_bf16(xl, wx_hi[i][3], xg3); xg3 = mfma_bf16(xh, wxlo[(i*4+3)*64], xg3);
                }
            }
        }
    }

    //==================== PHASE 2: layer 1 forward, 512 steps ====================
    {
        const int hs = (bid >> 2) & 63;    // 8 hidden units
        const int bt = bid & 3;

        // stage weights ONCE (wl reuse safe: block-local LDS, past loop-end barrier)
        short8 wh_hi2[4][2];
        #pragma unroll
        for (int i = 0; i < 4; ++i) {
            const int k0 = (w * 4 + i) * 32 + ks * 8;
            #pragma unroll
            for (int nt = 0; nt < 2; ++nt) {
                const int c = nt * 16 + lc;
                const int r = (c >> 3) * 512 + hs * 8 + (c & 7);
                short8 hi, lo;
                split8(&whh1f[(size_t)r * 512 + k0], hi, lo);
                wh_hi2[i][nt] = hi;
                wl[(w * 8 + i * 2 + nt) * 64 + l] = lo;
            }
        }
        short8 wx_hi2[8][2];
        #pragma unroll
        for (int i = 0; i < 8; ++i) {
            const int k0 = (w * 8 + i) * 32 + ks * 8;
            #pragma unroll
            for (int nt = 0; nt < 2; ++nt) {
                const int c = nt * 16 + lc;
                const int r = (c >> 3) * 512 + hs * 8 + (c & 7);
                short8 hi, lo;
                split8(&wih1f[(size_t)r * 1024 + k0], hi, lo);
                wx_hi2[i][nt] = hi;
                wl[2048 + (w * 16 + i * 2 + nt) * 64 + l] = lo;
            }
        }
        #pragma unroll
        for (int i = 0; i < 4; ++i)
            #pragma unroll
            for (int nt = 0; nt < 2; ++nt) pin8(wh_hi2[i][nt]);
        #pragma unroll
        for (int i = 0; i < 8; ++i)
            #pragma unroll
            for (int nt = 0; nt < 2; ++nt) pin8(wx_hi2[i][nt]);
        const short8* whlo2 = &wl[(w * 8) * 64 + l];
        const short8* wxlo2 = &wl[2048 + (w * 16) * 64 + l];

        const bool is_cell = (tid < 128);
        const int cb = bt * 16 + (tid >> 3);
        const int ch = hs * 8 + (tid & 7);
        float bias_r[4] = {0.f, 0.f, 0.f, 0.f};
        if (is_cell) {
            #pragma unroll
            for (int gt = 0; gt < 4; ++gt)
                bias_r[gt] = bih1f[gt * 512 + ch] + bhh1f[gt * 512 + ch];
        }
        float c_reg = 0.f;
        const int bA = bt * 16 + lc;

        // one-time gate: both same-bt P1 dir-groups done -> out0 fully visible
        if (tid < 64)
            poll_ge(&flags[(tid >> 5) * 128 + bt * 32 + (tid & 31)], (unsigned)Sn);
        __syncthreads();

        // xg for step 0
        f32x4 xg0 = {0.f,0.f,0.f,0.f}, xg1 = xg0;
        {
            unsigned ow[8][8];
            #pragma unroll
            for (int i = 0; i < 8; ++i)
                lda8(&out0_pk[(size_t)bA * Sn * 1024 + (w * 8 + i) * 32 + ks * 8], ow[i]);
            #pragma unroll
            for (int i = 0; i < 8; ++i) {
                short8 ah, al;
                unpack8(ow[i], ah, al);
                xg0 = mfma_bf16(ah, wx_hi2[i][0], xg0); xg0 = mfma_bf16(al, wx_hi2[i][0], xg0); xg0 = mfma_bf16(ah, wxlo2[(i*2+0)*64], xg0);
                xg1 = mfma_bf16(ah, wx_hi2[i][1], xg1); xg1 = mfma_bf16(al, wx_hi2[i][1], xg1); xg1 = mfma_bf16(ah, wxlo2[(i*2+1)*64], xg1);
            }
        }

        for (int s = 0; s < Sn; ++s) {
            const int p = s & 1;

            unsigned hw[4][8];
            #pragma unroll
            for (int i = 0; i < 4; ++i)
                poll8(&h1_tg[((size_t)p * Bn + bA) * Hn + (w * 4 + i) * 32 + ks * 8],
                      (unsigned)s, hw[i]);

            f32x4 acc0 = xg0, acc1 = xg1;
            #pragma unroll
            for (int i = 0; i < 4; ++i) {
                short8 ah, al;
                unpack8(hw[i], ah, al);
                acc0 = mfma_bf16(ah, wh_hi2[i][0], acc0); acc0 = mfma_bf16(al, wh_hi2[i][0], acc0); acc0 = mfma_bf16(ah, whlo2[(i*2+0)*64], acc0);
                acc1 = mfma_bf16(ah, wh_hi2[i][1], acc1); acc1 = mfma_bf16(al, wh_hi2[i][1], acc1); acc1 = mfma_bf16(ah, whlo2[(i*2+1)*64], acc1);
            }
            *(f32x4*)&P[((w * 2 + 0) * 16 + lc) * 20 + ks * 4] = acc0;
            *(f32x4*)&P[((w * 2 + 1) * 16 + lc) * 20 + ks * 4] = acc1;
            __syncthreads();

            if (is_cell) {
                float g4[4];
                #pragma unroll
                for (int gt = 0; gt < 4; ++gt) {
                    const int cc = gt * 8 + (tid & 7);
                    const int nt = cc >> 4, g = cc & 15;
                    float sum = bias_r[gt];
                    #pragma unroll
                    for (int ww = 0; ww < 4; ++ww)
                        sum += P[((ww * 2 + nt) * 16 + g) * 20 + (tid >> 3)];
                    g4[gt] = sum;
                }
                const float ig = 1.f / (1.f + expf(-g4[0]));
                const float fg = 1.f / (1.f + expf(-g4[1]));
                const float gg = tanhf(g4[2]);
                const float og = 1.f / (1.f + expf(-g4[3]));
                c_reg = fg * c_reg + ig * gg;
                const float h = og * tanhf(c_reg);
                const ushort hhv = f2bf(h);
                const ushort hlv = f2bf(h - bf2f(hhv));
                const unsigned word = (unsigned)hhv | ((unsigned)hlv << 16);
                st_tag(&h1_tg[((size_t)((s + 1) & 1) * Bn + cb) * Hn + ch],
                       word, (unsigned)(s + 1));
            }
            __syncthreads();

            // hoisted: next step's out0 projection
            if (s < Sn - 1) {
                unsigned ow[8][8];
                #pragma unroll
                for (int i = 0; i < 8; ++i)
                    lda8(&out0_pk[((size_t)bA * Sn + (s + 1)) * 1024 + (w * 8 + i) * 32 + ks * 8], ow[i]);
                xg0 = {0.f,0.f,0.f,0.f}; xg1 = xg0;
                #pragma unroll
                for (int i = 0; i < 8; ++i) {
                    short8 ah, al;
                    unpack8(ow[i], ah, al);
                    xg0 = mfma_bf16(ah, wx_hi2[i][0], xg0); xg0 = mfma_bf16(al, wx_hi2[i][0], xg0); xg0 = mfma_bf16(ah, wxlo2[(i*2+0)*64], xg0);
                    xg1 = mfma_bf16(ah, wx_hi2[i][1], xg1); xg1 = mfma_bf16(al, wx_hi2[i][1], xg1); xg1 = mfma_bf16(ah, wxlo2[(i*2+1)*64], xg1);
                }
            }
        }
    }

    //==================== PHASE 3: layer 1 backward, first step only (t = S-1) ====================
    {
        const int hs = (bid >> 2) & 63;
        const int bt = bid & 3;
        const int bA = bt * 16 + lc;
        const int t = Sn - 1;
        unsigned hw[8][8];
        #pragma unroll
        for (int i = 0; i < 8; ++i) {
            const int k0 = (w * 8 + i) * 32 + ks * 8;
            lda8(&out0_pk[((size_t)bA * Sn + t) * 1024 + k0], hw[i]);
        }
        f32x4 acc0 = {0.f,0.f,0.f,0.f}, acc1 = acc0;
        #pragma unroll
        for (int i = 0; i < 8; ++i) {
            const int k0 = (w * 8 + i) * 32 + ks * 8;
            short8 ah, al;
            unpack8(hw[i], ah, al);
            #pragma unroll
            for (int nt = 0; nt < 2; ++nt) {
                const int c = nt * 16 + lc;
                const int r = (c >> 3) * 512 + hs * 8 + (c & 7);
                short8 bh, bl;
                split8(&wih1b[(size_t)r * 1024 + k0], bh, bl);
                f32x4 a = (nt == 0) ? acc0 : acc1;
                a = mfma_bf16(ah, bh, a);
                a = mfma_bf16(al, bh, a);
                a = mfma_bf16(ah, bl, a);
                if (nt == 0) acc0 = a; else acc1 = a;
            }
        }
        *(f32x4*)&P[((w * 2 + 0) * 16 + lc) * 20 + ks * 4] = acc0;
        *(f32x4*)&P[((w * 2 + 1) * 16 + lc) * 20 + ks * 4] = acc1;
        __syncthreads();
        if (tid < 128) {
            const int cb = bt * 16 + (tid >> 3);
            const int ch = hs * 8 + (tid & 7);
            float g4[4];
            #pragma unroll
            for (int gt = 0; gt < 4; ++gt) {
                const int cc = gt * 8 + (tid & 7);
                const int nt = cc >> 4, g = cc & 15;
                float sum = bih1b[gt * 512 + ch] + bhh1b[gt * 512 + ch];
                #pragma unroll
                for (int ww = 0; ww < 4; ++ww)
                    sum += P[((ww * 2 + nt) * 16 + g) * 20 + (tid >> 3)];
                g4[gt] = sum;
            }
            const float ig = 1.f / (1.f + expf(-g4[0]));
            const float gg = tanhf(g4[2]);
            const float og = 1.f / (1.f + expf(-g4[3]));
            const float c = ig * gg;           // c_prev = 0
            const float h = og * tanhf(c);
            const ushort hhv = f2bf(h);
            const ushort hlv = f2bf(h - bf2f(hhv));
            sta32(&h1b_pk[(size_t)cb * Hn + ch], (unsigned)hhv | ((unsigned)hlv << 16));
        }
        __syncthreads();
        if (tid == 0)
            __hip_atomic_store(&flags[512 + bid], 1u, __ATOMIC_RELAXED, __HIP_MEMORY_SCOPE_AGENT);
    }

    //==================== PHASE 4: FC (blocks 0..63, after global wait) ====================
    if (bid < Bn) {
        if (tid < 256) poll_ge(&flags[512 + tid], 1u);
        __syncthreads();
        {
            // final forward h: parity 0 of h1_tg (tag 512), one element per u64
            const u64* qf = &h1_tg[(size_t)0 * Bn * Hn + (size_t)bid * Hn];
            u64 vf0 = __hip_atomic_load(qf + 2 * tid,     __ATOMIC_RELAXED, __HIP_MEMORY_SCOPE_AGENT);
            u64 vf1 = __hip_atomic_load(qf + 2 * tid + 1, __ATOMIC_RELAXED, __HIP_MEMORY_SCOPE_AGENT);
            const unsigned w0 = (unsigned)vf0, w1 = (unsigned)vf1;
            hstage[0][2 * tid]     = bf2f((ushort)(w0 & 0xffff)) + bf2f((ushort)(w0 >> 16));
            hstage[0][2 * tid + 1] = bf2f((ushort)(w1 & 0xffff)) + bf2f((ushort)(w1 >> 16));
            // backward-first h: packed u32, 2 elements per u64 load
            const u64* qb = (const u64*)&h1b_pk[(size_t)bid * Hn];
            u64 vb = __hip_atomic_load(qb + tid, __ATOMIC_RELAXED, __HIP_MEMORY_SCOPE_AGENT);
            hstage[1][2 * tid]     = bf2f((ushort)(vb & 0xffff))         + bf2f((ushort)((vb >> 16) & 0xffff));
            hstage[1][2 * tid + 1] = bf2f((ushort)((vb >> 32) & 0xffff)) + bf2f((ushort)((vb >> 48) & 0xffff));
        }
        __syncthreads();
        if (tid < On) {
            const int b = bid, o = tid;
            float sum = fcb[o];
            const float* wrow = &fcw[(size_t)o * 1024];
            #pragma unroll 4
            for (int j = 0; j < Hn; ++j) sum += hstage[0][j] * wrow[j];
            #pragma unroll 4
            for (int j = 0; j < Hn; ++j) sum += hstage[1][j] * wrow[512 + j];
            out[(size_t)b * On + o] = sum;
        }
    }
}

extern "C" void kernel_launch(void* const* d_in, const int* in_sizes, int n_in,
                              void* d_out, int out_size, void* d_ws, size_t ws_size,
                              hipStream_t stream)
{
    const float* x     = (const float*)d_in[0];
    const float* wih0f = (const float*)d_in[1];
    const float* whh0f = (const float*)d_in[2];
    const float* bih0f = (const float*)d_in[3];
    const float* bhh0f = (const float*)d_in[4];
    const float* wih0b = (const float*)d_in[5];
    const float* whh0b = (const float*)d_in[6];
    const float* bih0b = (const float*)d_in[7];
    const float* bhh0b = (const float*)d_in[8];
    const float* wih1f = (const float*)d_in[9];
    const float* whh1f = (const float*)d_in[10];
    const float* bih1f = (const float*)d_in[11];
    const float* bhh1f = (const float*)d_in[12];
    const float* wih1b = (const float*)d_in[13];
    const float* whh1b = (const float*)d_in[14];
    const float* bih1b = (const float*)d_in[15];
    const float* bhh1b = (const float*)d_in[16];
    const float* fcw   = (const float*)d_in[17];
    const float* fcb   = (const float*)d_in[18];

    char* ws = (char*)d_ws;
    size_t off = 0;
    unsigned* flags = (unsigned*)(ws + off); off += (size_t)768 * 4;
    u64* h0_tg = (u64*)(ws + off); off += (size_t)2 * 2 * Bn * Hn * 8;
    u64* h1_tg = (u64*)(ws + off); off += (size_t)2 * Bn * Hn * 8;
    size_t zero_end = off;                    // flags + tagged h state must start zeroed
    unsigned* h1b_pk = (unsigned*)(ws + off); off += (size_t)Bn * Hn * 4;
    unsigned* out0_pk = (unsigned*)(ws + off); off += (size_t)Bn * Sn * 2 * Hn * 4;

    hipMemsetAsync(d_ws, 0, zero_end, stream);

    hipLaunchKernelGGL(bilstm_persistent, dim3(256), dim3(256), 0, stream,
        x, wih0f, whh0f, bih0f, bhh0f, wih0b, whh0b, bih0b, bhh0b,
        wih1f, whh1f, bih1f, bhh1f, wih1b, whh1b, bih1b, bhh1b,
        fcw, fcb,
        flags, h0_tg, h1_tg, h1b_pk, out0_pk,
        (float*)d_out);
}